// Round 3
// baseline (174.681 us; speedup 1.0000x reference)
//
#include <hip/hip_runtime.h>
#include <stdint.h>

// Problem constants
#define B_  1024
#define D_  512
#define K_  255
#define L_  256
#define C_  80

typedef __attribute__((ext_vector_type(8))) short bf16x8;
typedef __attribute__((ext_vector_type(4))) float f32x4;
typedef __attribute__((ext_vector_type(8))) short short8;

// async global->LDS, 16B per lane; dst must be wave-uniform base + lane*16.
#define GLD(gsrc, ldst) \
  __builtin_amdgcn_global_load_lds((const __attribute__((address_space(1))) void*)(gsrc), \
                                   (__attribute__((address_space(3))) void*)(ldst), 16, 0, 0)

// counted vmcnt wait + raw barrier (T4: never drain vmcnt(0) in steady state)
#define WAITV_(n) asm volatile("s_waitcnt vmcnt(" #n ")" ::: "memory")
#define WAITV(n)  WAITV_(n)
#define BARR() do { __builtin_amdgcn_s_barrier(); \
                    asm volatile("" ::: "memory"); \
                    __builtin_amdgcn_sched_barrier(0); } while (0)

__device__ __forceinline__ short cvt_bf16(float f) {
    unsigned u = __float_as_uint(f);
    u += 0x7FFFu + ((u >> 16) & 1u);
    return (short)(u >> 16);
}

// ---------------------------------------------------------------------------
// Kernel 1: convert W (20480x512) + x (1024x512) fp32->bf16, AND normalize
// ne rows -> bf16 neb (256 rows; row 255 zeroed).  Memory-bound (~66 MB).
// ---------------------------------------------------------------------------
__global__ __launch_bounds__(256) void convert_kernel(const float* __restrict__ w,
                                                      const float* __restrict__ x,
                                                      const float* __restrict__ ne,
                                                      short* __restrict__ wb,
                                                      short* __restrict__ xb,
                                                      short* __restrict__ neb) {
    __shared__ float red[256];
    const int tid = threadIdx.x;
    if (blockIdx.x < 2048) {
        size_t i0 = (size_t)blockIdx.x * 256 + tid;
        const size_t stride = 2048u * 256u;
        for (size_t v = i0; v < 1310720u; v += stride) {
            float4 a = ((const float4*)w)[v * 2];
            float4 b = ((const float4*)w)[v * 2 + 1];
            short8 o;
            o[0] = cvt_bf16(a.x); o[1] = cvt_bf16(a.y); o[2] = cvt_bf16(a.z); o[3] = cvt_bf16(a.w);
            o[4] = cvt_bf16(b.x); o[5] = cvt_bf16(b.y); o[6] = cvt_bf16(b.z); o[7] = cvt_bf16(b.w);
            ((short8*)wb)[v] = o;
        }
        for (size_t v = i0; v < 65536u; v += stride) {
            float4 a = ((const float4*)x)[v * 2];
            float4 b = ((const float4*)x)[v * 2 + 1];
            short8 o;
            o[0] = cvt_bf16(a.x); o[1] = cvt_bf16(a.y); o[2] = cvt_bf16(a.z); o[3] = cvt_bf16(a.w);
            o[4] = cvt_bf16(b.x); o[5] = cvt_bf16(b.y); o[6] = cvt_bf16(b.z); o[7] = cvt_bf16(b.w);
            ((short8*)xb)[v] = o;
        }
    } else {
        const int row = blockIdx.x - 2048;  // 0..255
        if (row == 255) {
            ((unsigned*)(neb + 255 * 512))[tid] = 0u;  // pad row = zeros
            return;
        }
        const float2* nr = (const float2*)(ne + (size_t)row * 512);
        float2 a = nr[tid];
        red[tid] = a.x * a.x + a.y * a.y;
        __syncthreads();
        #pragma unroll
        for (int s = 128; s > 0; s >>= 1) {
            if (tid < s) red[tid] += red[tid + s];
            __syncthreads();
        }
        float inv = rsqrtf(red[0]);
        unsigned lo = (unsigned short)cvt_bf16(a.x * inv);
        unsigned hi = (unsigned short)cvt_bf16(a.y * inv);
        ((unsigned*)(neb + (size_t)row * 512))[tid] = lo | (hi << 16);
    }
}

// ---------------------------------------------------------------------------
// Kernel 2: sim GEMM: out1[b,k] = sigmoid(xb[b,:]·neb[k,:]). 64x64 tiles.
// ---------------------------------------------------------------------------
__global__ __launch_bounds__(256) void simgemm_kernel(const short* __restrict__ xb,
                                                      const short* __restrict__ neb,
                                                      float* __restrict__ out1) {
    __shared__ __align__(16) short Ald[512 * 8];
    __shared__ __align__(16) short Bld[512 * 8];
    const int tid = threadIdx.x;
    const int lane = tid & 63, wave = tid >> 6;
    const int q = lane >> 4, r = lane & 15;
    const int mt = blockIdx.x >> 2;
    const int nt = blockIdx.x & 3;

    f32x4 acc[4];
    #pragma unroll
    for (int nf = 0; nf < 4; ++nf) acc[nf] = (f32x4){0.f, 0.f, 0.f, 0.f};

    const bf16x8* Av = (const bf16x8*)Ald;
    const bf16x8* Bv = (const bf16x8*)Bld;

    for (int kb = 0; kb < 8; ++kb) {
        __syncthreads();
        #pragma unroll
        for (int j = 0; j < 2; ++j) {
            int ph = j * 256 + tid, rr = ph >> 3, g = (ph & 7) ^ (rr & 7);
            GLD(xb + ((size_t)(mt * 64 + rr) * D_ + kb * 64 + g * 8), Ald + ph * 8);
        }
        #pragma unroll
        for (int j = 0; j < 2; ++j) {
            int ph = j * 256 + tid, cc = ph >> 3, g = (ph & 7) ^ (cc & 7);
            GLD(neb + ((size_t)(nt * 64 + cc) * D_ + kb * 64 + g * 8), Bld + ph * 8);
        }
        __syncthreads();
        #pragma unroll
        for (int ks = 0; ks < 2; ++ks) {
            const int g = ks * 4 + q;
            int rl = wave * 16 + r;
            bf16x8 af = Av[rl * 8 + (g ^ (rl & 7))];
            #pragma unroll
            for (int nf = 0; nf < 4; ++nf) {
                int cl = nf * 16 + r;
                bf16x8 bfr = Bv[cl * 8 + (g ^ (cl & 7))];
                acc[nf] = __builtin_amdgcn_mfma_f32_16x16x32_bf16(af, bfr, acc[nf], 0, 0, 0);
            }
        }
    }
    #pragma unroll
    for (int nf = 0; nf < 4; ++nf) {
        int gcol = nt * 64 + nf * 16 + r;
        if (gcol < K_) {
            #pragma unroll
            for (int i = 0; i < 4; ++i) {
                int grow = mt * 64 + wave * 16 + q * 4 + i;
                out1[(size_t)grow * K_ + gcol] = 1.f / (1.f + __expf(-acc[nf][i]));
            }
        }
    }
}

// ---------------------------------------------------------------------------
// Kernel 3: leaf probabilities from out1 sigmoids. Block = batch row.
// Also zeroes out0 (runs before gemm; gemm atomicAdds into it).
// ---------------------------------------------------------------------------
__global__ __launch_bounds__(256) void leafprob_kernel(const float* __restrict__ out1,
                                                       float* __restrict__ p_ws,
                                                       float* __restrict__ out0) {
    __shared__ float ss[K_];
    const int b = blockIdx.x, t = threadIdx.x;
    if (t < K_) ss[t] = out1[(size_t)b * K_ + t];
    if (t < C_) out0[(size_t)b * C_ + t] = 0.f;   // zero-init for gemm atomics
    __syncthreads();
    float prob = 1.f;
    int node = 0;
    #pragma unroll
    for (int d = 0; d < 8; ++d) {
        int bit = (t >> (7 - d)) & 1;
        float s = ss[node];
        prob *= bit ? (1.f - s) : s;
        node = 2 * node + 1 + bit;
    }
    p_ws[(size_t)b * L_ + t] = prob;
}

// ---------------------------------------------------------------------------
// Kernel 4: main GEMM — counted-vmcnt pipeline (T3/T4).
// Round-3 theory: round-2 was latency-bound (all pipes <20%): every region's
// barrier drained vmcnt(0) on loads issued only ~400cyc earlier -> ~1300cyc
// exposed stall/region. Fix: 2-region-deep prefetch with counted waits.
//   - B triple-buffered (3 x 96rows x 64K = 3 x 12KB; rows padded 80->96 so
//     every wave issues exactly 3 GLD/region -> wave-uniform vmcnt counts;
//     pad rows read harmless garbage, never ds_read).
//   - A double-buffered (2 x 16KB), staged once per kc (at li==2, 2 ahead).
//   - Region R: WAITV(N); raw s_barrier; issue stage for R+2; compute.
//     Issue-after-barrier is race-free: buf (R+2)%3 was last read in region
//     R-1, and the barrier at R retires all waves' R-1 reads. N=3 (only R-1's
//     B-issue outstanding) or 7 at li==3 (R-1 issued B+A). kc=7 peeled:
//     N=3,3,3,0. Prologue: outacc init from GLOBAL p (so compiler waits
//     don't drain prefetch), then A(0),B(0),B(1) issued; lgkmcnt(0) before
//     first barrier covers the p_ld ds_writes.
//   - Epilogue: atomicAdd into out0 directly (reduce kernel deleted; out0
//     zeroed by leafprob). Removes 21MB partial write + 22MB re-read.
// LDS: A 32KB + B 36KB + p 2KB = 70KB -> 2 blocks/CU. VGPR ~125, cap 256 at
// (256,2) so no spill risk even if allocator goes higher.
// Grid = mt(8) x lc(64); blockIdx%8 = lc%8 keeps the 8 m-tiles sharing a W
// slab on one XCD (L2-resident).
// ---------------------------------------------------------------------------
__global__ __launch_bounds__(256, 2) void gemm_kernel(const short* __restrict__ xb,
                                                      const short* __restrict__ wb,
                                                      const float* __restrict__ p,
                                                      const float* __restrict__ lb,
                                                      float* __restrict__ out0) {
    __shared__ __align__(16) short Ald[2 * 1024 * 8];  // 2 x (128 rows x 8 granules) = 32 KB
    __shared__ __align__(16) short Bld[3 * 768 * 8];   // 3 x ( 96 rows x 8 granules) = 36 KB
    __shared__ float p_ld[128][4];                     // 2 KB

    const int tid = threadIdx.x;
    const int lane = tid & 63, wave = tid >> 6;
    const int q = lane >> 4, r = lane & 15;
    const int wrow = wave * 32;
    const int lc = blockIdx.x & 63;   // 64 l-chunks of 4 leaves
    const int mt = blockIdx.x >> 6;   // 8 m-tiles of 128 rows

    // ---- outacc init = bias term, from GLOBAL p (transient regs; issued
    // before any GLD so the compiler's waits here cannot drain the prefetch)
    f32x4 outacc[2][5];
    #pragma unroll
    for (int mf = 0; mf < 2; ++mf)
        #pragma unroll
        for (int i = 0; i < 4; ++i) {
            int row = mt * 128 + wrow + mf * 16 + q * 4 + i;
            float4 pw = *(const float4*)(p + (size_t)row * L_ + lc * 4);
            #pragma unroll
            for (int nf = 0; nf < 5; ++nf) {
                float s = pw.x * lb[(size_t)(lc * 4 + 0) * C_ + nf * 16 + r]
                        + pw.y * lb[(size_t)(lc * 4 + 1) * C_ + nf * 16 + r]
                        + pw.z * lb[(size_t)(lc * 4 + 2) * C_ + nf * 16 + r]
                        + pw.w * lb[(size_t)(lc * 4 + 3) * C_ + nf * 16 + r];
                outacc[mf][nf][i] = s;
            }
        }

    // ---- p tile to LDS (for the per-region folds)
    if (tid < 128) {
        float4 pw = *(const float4*)(p + (size_t)(mt * 128 + tid) * L_ + lc * 4);
        p_ld[tid][0] = pw.x; p_ld[tid][1] = pw.y;
        p_ld[tid][2] = pw.z; p_ld[tid][3] = pw.w;
    }

    // ---- stage helpers. A: 1024 granules (128r x 8g), 4 GLD/thread.
    // B: 768 granules (96r x 8g, padded), 3 GLD/thread. XOR-swizzle g^(row&7)
    // keeps ds_read_b128 conflict-free.
    auto stageA = [&](int buf, int kc) {
        #pragma unroll
        for (int j = 0; j < 4; ++j) {
            int ph = j * 256 + tid;
            int rr = ph >> 3;
            int g  = (ph & 7) ^ (rr & 7);
            GLD(xb + ((size_t)(mt * 128 + rr)) * D_ + kc * 64 + g * 8,
                Ald + (buf * 1024 + ph) * 8);
        }
    };
    auto stageB = [&](int buf, int l, int kc) {
        #pragma unroll
        for (int j = 0; j < 3; ++j) {
            int ph = j * 256 + tid;
            int cc = ph >> 3;                    // 0..95 (80..95 = pad rows)
            int g  = (ph & 7) ^ (cc & 7);
            GLD(wb + ((size_t)l * C_ + cc) * D_ + kc * 64 + g * 8,
                Bld + (buf * 768 + ph) * 8);
        }
    };

    const f32x4 z4 = {0.f, 0.f, 0.f, 0.f};

    auto computeR = [&](int ab, int bb, int li) {
        const bf16x8* Av = (const bf16x8*)Ald + ab * 1024;
        const bf16x8* Bv = (const bf16x8*)Bld + bb * 768;
        f32x4 dec[2][5];
        #pragma unroll
        for (int ks = 0; ks < 2; ++ks) {
            const int g = ks * 4 + q;
            bf16x8 af[2], bfr[5];
            #pragma unroll
            for (int mf = 0; mf < 2; ++mf) {
                int rl = wrow + mf * 16 + r;
                af[mf] = Av[rl * 8 + (g ^ (rl & 7))];
            }
            #pragma unroll
            for (int nf = 0; nf < 5; ++nf) {
                int cl = nf * 16 + r;
                bfr[nf] = Bv[cl * 8 + (g ^ (cl & 7))];
            }
            #pragma unroll
            for (int mf = 0; mf < 2; ++mf)
                #pragma unroll
                for (int nf = 0; nf < 5; ++nf)
                    dec[mf][nf] = __builtin_amdgcn_mfma_f32_16x16x32_bf16(
                        af[mf], bfr[nf], ks == 0 ? z4 : dec[mf][nf], 0, 0, 0);
        }
        #pragma unroll
        for (int mf = 0; mf < 2; ++mf)
            #pragma unroll
            for (int i = 0; i < 4; ++i) {
                float pf = p_ld[wrow + mf * 16 + q * 4 + i][li];
                #pragma unroll
                for (int nf = 0; nf < 5; ++nf)
                    outacc[mf][nf][i] += pf * dec[mf][nf][i];
            }
    };

    // ---- prologue: issue A(0), B(R0), B(R1); drain only lgkm (p_ld writes)
    stageA(0, 0);
    stageB(0, lc * 4 + 0, 0);
    stageB(1, lc * 4 + 1, 0);
    asm volatile("s_waitcnt lgkmcnt(0)" ::: "memory");

    int bb = 0;  // B buffer of the CURRENT region (rotates mod 3)
    #define NX(b)  ((b) + 1 == 3 ? 0 : (b) + 1)
    #define NX2(b) ((b) + 2 >= 3 ? (b) - 1 : (b) + 2)

    for (int kc = 0; kc < 7; ++kc) {
        const int ab = kc & 1;
        // li = 0: prev site issued 3 (B) -> allow 3 outstanding
        WAITV(3); BARR();
        stageB(NX2(bb), lc * 4 + 2, kc);
        computeR(ab, bb, 0); bb = NX(bb);
        // li = 1
        WAITV(3); BARR();
        stageB(NX2(bb), lc * 4 + 3, kc);
        computeR(ab, bb, 1); bb = NX(bb);
        // li = 2: issue next kc's first B AND next A (7 outstanding after)
        WAITV(3); BARR();
        stageB(NX2(bb), lc * 4 + 0, kc + 1);
        stageA(ab ^ 1, kc + 1);
        computeR(ab, bb, 2); bb = NX(bb);
        // li = 3: prev site issued B(3)+A(4) -> allow 7
        WAITV(7); BARR();
        stageB(NX2(bb), lc * 4 + 1, kc + 1);
        computeR(ab, bb, 3); bb = NX(bb);
    }
    // ---- peeled kc = 7 (no further A; B issues taper off)
    {
        WAITV(3); BARR();
        stageB(NX2(bb), lc * 4 + 2, 7);
        computeR(1, bb, 0); bb = NX(bb);

        WAITV(3); BARR();
        stageB(NX2(bb), lc * 4 + 3, 7);
        computeR(1, bb, 1); bb = NX(bb);

        WAITV(3); BARR();
        computeR(1, bb, 2); bb = NX(bb);

        WAITV(0); BARR();
        computeR(1, bb, 3);
    }
    #undef NX
    #undef NX2

    // ---- epilogue: fire-and-forget atomics into out0 (zeroed by leafprob)
    #pragma unroll
    for (int mf = 0; mf < 2; ++mf)
        #pragma unroll
        for (int nf = 0; nf < 5; ++nf)
            #pragma unroll
            for (int i = 0; i < 4; ++i) {
                int row = mt * 128 + wrow + mf * 16 + q * 4 + i;
                int col = nf * 16 + r;
                atomicAdd(out0 + (size_t)row * C_ + col, outacc[mf][nf][i]);
            }
}

// ---------------------------------------------------------------------------
extern "C" void kernel_launch(void* const* d_in, const int* in_sizes, int n_in,
                              void* d_out, int out_size, void* d_ws, size_t ws_size,
                              hipStream_t stream) {
    const float* x  = (const float*)d_in[0];  // 1024x512
    const float* ne = (const float*)d_in[1];  // 255x512
    const float* lW = (const float*)d_in[2];  // 20480x512
    const float* lb = (const float*)d_in[3];  // 20480
    // d_in[4] res_path: deterministic structure, traversed directly

    float* out0 = (float*)d_out;            // 1024x80
    float* out1 = out0 + (size_t)B_ * C_;   // 1024x255

    char* ws = (char*)d_ws;
    short* xb   = (short*)ws;                             // 1 MB
    short* neb  = (short*)(ws + (1u << 20));              // 256 KB
    float* p_ws = (float*)(ws + (1u << 20) + (1u << 18)); // 1 MB
    short* wb   = (short*)(ws + (9u << 18));              // 20 MB @ 2.25 MB (+pad slack)

    convert_kernel<<<2304, 256, 0, stream>>>(lW, x, ne, wb, xb, neb);
    simgemm_kernel<<<64, 256, 0, stream>>>(xb, neb, out1);
    leafprob_kernel<<<B_, 256, 0, stream>>>(out1, p_ws, out0);
    gemm_kernel<<<512, 256, 0, stream>>>(xb, wb, p_ws, lb, out0);
}

// Round 4
// 140.502 us; speedup vs baseline: 1.2433x; 1.2433x over previous
//
#include <hip/hip_runtime.h>
#include <stdint.h>

// Problem constants
#define B_  1024
#define D_  512
#define K_  255
#define L_  256
#define C_  80

typedef __attribute__((ext_vector_type(8))) short bf16x8;
typedef __attribute__((ext_vector_type(4))) float f32x4;
typedef __attribute__((ext_vector_type(8))) short short8;

// async global->LDS, 16B per lane; dst must be wave-uniform base + lane*16.
#define GLD(gsrc, ldst) \
  __builtin_amdgcn_global_load_lds((const __attribute__((address_space(1))) void*)(gsrc), \
                                   (__attribute__((address_space(3))) void*)(ldst), 16, 0, 0)

__device__ __forceinline__ short cvt_bf16(float f) {
    unsigned u = __float_as_uint(f);
    u += 0x7FFFu + ((u >> 16) & 1u);
    return (short)(u >> 16);
}

// ---------------------------------------------------------------------------
// Kernel 1: convert W (20480x512) + x (1024x512) fp32->bf16, AND normalize
// ne rows -> bf16 neb (256 rows; row 255 zeroed).  Memory-bound (~66 MB).
// ---------------------------------------------------------------------------
__global__ __launch_bounds__(256) void convert_kernel(const float* __restrict__ w,
                                                      const float* __restrict__ x,
                                                      const float* __restrict__ ne,
                                                      short* __restrict__ wb,
                                                      short* __restrict__ xb,
                                                      short* __restrict__ neb) {
    __shared__ float red[256];
    const int tid = threadIdx.x;
    if (blockIdx.x < 2048) {
        size_t i0 = (size_t)blockIdx.x * 256 + tid;
        const size_t stride = 2048u * 256u;
        for (size_t v = i0; v < 1310720u; v += stride) {
            float4 a = ((const float4*)w)[v * 2];
            float4 b = ((const float4*)w)[v * 2 + 1];
            short8 o;
            o[0] = cvt_bf16(a.x); o[1] = cvt_bf16(a.y); o[2] = cvt_bf16(a.z); o[3] = cvt_bf16(a.w);
            o[4] = cvt_bf16(b.x); o[5] = cvt_bf16(b.y); o[6] = cvt_bf16(b.z); o[7] = cvt_bf16(b.w);
            ((short8*)wb)[v] = o;
        }
        for (size_t v = i0; v < 65536u; v += stride) {
            float4 a = ((const float4*)x)[v * 2];
            float4 b = ((const float4*)x)[v * 2 + 1];
            short8 o;
            o[0] = cvt_bf16(a.x); o[1] = cvt_bf16(a.y); o[2] = cvt_bf16(a.z); o[3] = cvt_bf16(a.w);
            o[4] = cvt_bf16(b.x); o[5] = cvt_bf16(b.y); o[6] = cvt_bf16(b.z); o[7] = cvt_bf16(b.w);
            ((short8*)xb)[v] = o;
        }
    } else {
        const int row = blockIdx.x - 2048;  // 0..255
        if (row == 255) {
            ((unsigned*)(neb + 255 * 512))[tid] = 0u;  // pad row = zeros
            return;
        }
        const float2* nr = (const float2*)(ne + (size_t)row * 512);
        float2 a = nr[tid];
        red[tid] = a.x * a.x + a.y * a.y;
        __syncthreads();
        #pragma unroll
        for (int s = 128; s > 0; s >>= 1) {
            if (tid < s) red[tid] += red[tid + s];
            __syncthreads();
        }
        float inv = rsqrtf(red[0]);
        unsigned lo = (unsigned short)cvt_bf16(a.x * inv);
        unsigned hi = (unsigned short)cvt_bf16(a.y * inv);
        ((unsigned*)(neb + (size_t)row * 512))[tid] = lo | (hi << 16);
    }
}

// ---------------------------------------------------------------------------
// Kernel 2: sim GEMM: out1[b,k] = sigmoid(xb[b,:]·neb[k,:]). 64x64 tiles.
// ---------------------------------------------------------------------------
__global__ __launch_bounds__(256) void simgemm_kernel(const short* __restrict__ xb,
                                                      const short* __restrict__ neb,
                                                      float* __restrict__ out1) {
    __shared__ __align__(16) short Ald[512 * 8];
    __shared__ __align__(16) short Bld[512 * 8];
    const int tid = threadIdx.x;
    const int lane = tid & 63, wave = tid >> 6;
    const int q = lane >> 4, r = lane & 15;
    const int mt = blockIdx.x >> 2;
    const int nt = blockIdx.x & 3;

    f32x4 acc[4];
    #pragma unroll
    for (int nf = 0; nf < 4; ++nf) acc[nf] = (f32x4){0.f, 0.f, 0.f, 0.f};

    const bf16x8* Av = (const bf16x8*)Ald;
    const bf16x8* Bv = (const bf16x8*)Bld;

    for (int kb = 0; kb < 8; ++kb) {
        __syncthreads();
        #pragma unroll
        for (int j = 0; j < 2; ++j) {
            int ph = j * 256 + tid, rr = ph >> 3, g = (ph & 7) ^ (rr & 7);
            GLD(xb + ((size_t)(mt * 64 + rr) * D_ + kb * 64 + g * 8), Ald + ph * 8);
        }
        #pragma unroll
        for (int j = 0; j < 2; ++j) {
            int ph = j * 256 + tid, cc = ph >> 3, g = (ph & 7) ^ (cc & 7);
            GLD(neb + ((size_t)(nt * 64 + cc) * D_ + kb * 64 + g * 8), Bld + ph * 8);
        }
        __syncthreads();
        #pragma unroll
        for (int ks = 0; ks < 2; ++ks) {
            const int g = ks * 4 + q;
            int rl = wave * 16 + r;
            bf16x8 af = Av[rl * 8 + (g ^ (rl & 7))];
            #pragma unroll
            for (int nf = 0; nf < 4; ++nf) {
                int cl = nf * 16 + r;
                bf16x8 bfr = Bv[cl * 8 + (g ^ (cl & 7))];
                acc[nf] = __builtin_amdgcn_mfma_f32_16x16x32_bf16(af, bfr, acc[nf], 0, 0, 0);
            }
        }
    }
    #pragma unroll
    for (int nf = 0; nf < 4; ++nf) {
        int gcol = nt * 64 + nf * 16 + r;
        if (gcol < K_) {
            #pragma unroll
            for (int i = 0; i < 4; ++i) {
                int grow = mt * 64 + wave * 16 + q * 4 + i;
                out1[(size_t)grow * K_ + gcol] = 1.f / (1.f + __expf(-acc[nf][i]));
            }
        }
    }
}

// ---------------------------------------------------------------------------
// Kernel 3: leaf probabilities from out1 sigmoids. Block = batch row.
// Also zeroes out0 (runs before gemm/reduce; reduce atomicAdds into it).
// ---------------------------------------------------------------------------
__global__ __launch_bounds__(256) void leafprob_kernel(const float* __restrict__ out1,
                                                       float* __restrict__ p_ws,
                                                       float* __restrict__ out0) {
    __shared__ float ss[K_];
    const int b = blockIdx.x, t = threadIdx.x;
    if (t < K_) ss[t] = out1[(size_t)b * K_ + t];
    if (t < C_) out0[(size_t)b * C_ + t] = 0.f;   // zero-init for reduce atomics
    __syncthreads();
    float prob = 1.f;
    int node = 0;
    #pragma unroll
    for (int d = 0; d < 8; ++d) {
        int bit = (t >> (7 - d)) & 1;
        float s = ss[node];
        prob *= bit ? (1.f - s) : s;
        node = 2 * node + 1 + bit;
    }
    p_ws[(size_t)b * L_ + t] = prob;
}

// ---------------------------------------------------------------------------
// Kernel 4: main GEMM — ROUND-0 STRUCTURE RESTORED (the fastest measured),
// with one strictly-local change.
// Round-4 theory: round-0's rhythm (__syncthreads; stage; __syncthreads;
// compute 40 MFMA) beat every restructure because the vmcnt(0) drain at the
// barrier is amortized over 2x the MFMA work, and the co-resident block
// covers the drain. Round-3's counted-vmcnt + sched_barrier pinning and
// 64-way-contended atomic epilogue both regressed — reverted.
// Local change vs round 0: kb-OUTER / li-INNER so the A-tile (depends only
// on kb) is staged 4x instead of 16x; 12 of 16 stages then stage only B
// (20 KB, not 52 KB) -> shorter drains, -96 GLD/thread. Per-stage sync
// structure is IDENTICAL to round-0. p-fold per (kb,li) chunk is linear
// (outacc += p*dec_chunk), bias folded at init — both numerically validated
// in rounds 1-3 (absmax unchanged at 0.0039).
// Register shape = round-2's proven no-spill layout (outacc 40 + dec 40 +
// frags 28 -> VGPR 128). LDS: A 32 KB + B 20 KB + p 2 KB = 54 KB -> 2
// blocks/CU at __launch_bounds__(256,2).
// Grid = mt(8) x lc(64) = 512 blocks; blockIdx%8 = lc%8 keeps the 8 m-tiles
// sharing a W slab on one XCD (~2.6 MB/XCD, L2-resident).
// ---------------------------------------------------------------------------
__global__ __launch_bounds__(256, 2) void gemm_kernel(const short* __restrict__ xb,
                                                      const short* __restrict__ wb,
                                                      const float* __restrict__ p,
                                                      const float* __restrict__ lb,
                                                      float* __restrict__ partial) {
    __shared__ __align__(16) short Ald[2048 * 8];  // 128 rows x 16 granules = 32 KB
    __shared__ __align__(16) short Bld[1280 * 8];  // 80 rows x 16 granules = 20 KB
    __shared__ float p_ld[128][4];                 // 2 KB

    const int tid = threadIdx.x;
    const int lane = tid & 63, wave = tid >> 6;
    const int q = lane >> 4, r = lane & 15;
    const int wrow = wave * 32;
    const int lc = blockIdx.x & 63;   // 64 l-chunks of 4 leaves
    const int mt = blockIdx.x >> 6;   // 8 m-tiles of 128 rows

    if (tid < 128) {
        float4 pw = *(const float4*)(p + (size_t)(mt * 128 + tid) * L_ + lc * 4);
        p_ld[tid][0] = pw.x; p_ld[tid][1] = pw.y;
        p_ld[tid][2] = pw.z; p_ld[tid][3] = pw.w;
    }
    __syncthreads();  // p_ld visible

    // outacc init = bias term: sum_li p_ld[row][li] * lb[(lc*4+li)*80 + col]
    f32x4 outacc[2][5];
    #pragma unroll
    for (int nf = 0; nf < 5; ++nf) {
        float bv[4];
        #pragma unroll
        for (int li = 0; li < 4; ++li)
            bv[li] = lb[(size_t)(lc * 4 + li) * C_ + nf * 16 + r];
        #pragma unroll
        for (int mf = 0; mf < 2; ++mf)
            #pragma unroll
            for (int i = 0; i < 4; ++i) {
                int row = wrow + mf * 16 + q * 4 + i;
                outacc[mf][nf][i] = p_ld[row][0] * bv[0] + p_ld[row][1] * bv[1]
                                  + p_ld[row][2] * bv[2] + p_ld[row][3] * bv[3];
            }
    }

    const bf16x8* Av = (const bf16x8*)Ald;
    const bf16x8* Bv = (const bf16x8*)Bld;
    const f32x4 z4 = {0.f, 0.f, 0.f, 0.f};

    for (int kb = 0; kb < 4; ++kb) {      // 4 K=128 chunks, A staged once each
        for (int li = 0; li < 4; ++li) {  // 4 leaves, B staged per (kb,li)
            __syncthreads();  // previous stage's readers done before overwrite
            if (li == 0) {
                // stage A: 2048 granules (128 rows x 16), 8 per thread
                #pragma unroll
                for (int j = 0; j < 8; ++j) {
                    int ph = j * 256 + tid;
                    int rr = ph >> 4;
                    int g  = (ph & 15) ^ (rr & 15);
                    GLD(xb + ((size_t)(mt * 128 + rr) * D_ + kb * 128 + g * 8), Ald + ph * 8);
                }
            }
            // stage B: 1280 granules (80 rows x 16), 5 per thread
            #pragma unroll
            for (int j = 0; j < 5; ++j) {
                int ph = j * 256 + tid;
                int cc = ph >> 4;
                int g  = (ph & 15) ^ (cc & 15);
                GLD(wb + ((size_t)((lc * 4 + li) * C_ + cc) * D_ + kb * 128 + g * 8), Bld + ph * 8);
            }
            __syncthreads();  // drains vmcnt(0): tiles complete

            f32x4 dec[2][5];
            #pragma unroll
            for (int ks = 0; ks < 4; ++ks) {  // 4 K=32 slices -> 40 MFMA/stage
                const int g = ks * 4 + q;
                bf16x8 af[2], bfr[5];
                #pragma unroll
                for (int mf = 0; mf < 2; ++mf) {
                    int rl = wrow + mf * 16 + r;
                    af[mf] = Av[rl * 16 + (g ^ (rl & 15))];
                }
                #pragma unroll
                for (int nf = 0; nf < 5; ++nf) {
                    int cl = nf * 16 + r;
                    bfr[nf] = Bv[cl * 16 + (g ^ (cl & 15))];
                }
                #pragma unroll
                for (int mf = 0; mf < 2; ++mf)
                    #pragma unroll
                    for (int nf = 0; nf < 5; ++nf)
                        dec[mf][nf] = __builtin_amdgcn_mfma_f32_16x16x32_bf16(
                            af[mf], bfr[nf], ks == 0 ? z4 : dec[mf][nf], 0, 0, 0);
            }

            // linear p-fold of this (kb,li) chunk; p read from LDS
            #pragma unroll
            for (int mf = 0; mf < 2; ++mf)
                #pragma unroll
                for (int i = 0; i < 4; ++i) {
                    float pf = p_ld[wrow + mf * 16 + q * 4 + i][li];
                    #pragma unroll
                    for (int nf = 0; nf < 5; ++nf)
                        outacc[mf][nf][i] += pf * dec[mf][nf][i];
                }
        }
    }

    // store partials: partial[lc][1024 rows][80 cols], this block owns 128 rows
    const size_t rbase = (size_t)lc * B_ + mt * 128;
    #pragma unroll
    for (int mf = 0; mf < 2; ++mf)
        #pragma unroll
        for (int nf = 0; nf < 5; ++nf)
            #pragma unroll
            for (int i = 0; i < 4; ++i) {
                int row = wrow + mf * 16 + q * 4 + i;
                int col = nf * 16 + r;
                partial[(rbase + row) * C_ + col] = outacc[mf][nf][i];
            }
}

// ---------------------------------------------------------------------------
// Kernel 5: reduce 64 lc partials -> out0 (1024x80).
// Grid 640 = 80 idx-chunks x 8 j-groups: each thread sums 8 slabs and
// atomicAdds (8-way contention only; out0 zeroed by leafprob).
// ---------------------------------------------------------------------------
__global__ __launch_bounds__(256) void reduce_kernel(const float* __restrict__ partial,
                                                     float* __restrict__ out0) {
    const int chunk = blockIdx.x >> 3;            // 0..79
    const int jg    = blockIdx.x & 7;             // 0..7
    const int idx   = chunk * 256 + threadIdx.x;  // float4 index < 20480
    const float4* p4 = (const float4*)partial;
    float4 s = {0.f, 0.f, 0.f, 0.f};
    #pragma unroll
    for (int j = 0; j < 8; ++j) {
        float4 v = p4[(size_t)(jg * 8 + j) * (B_ * C_ / 4) + idx];
        s.x += v.x; s.y += v.y; s.z += v.z; s.w += v.w;
    }
    float* o = out0 + (size_t)idx * 4;
    atomicAdd(o + 0, s.x);
    atomicAdd(o + 1, s.y);
    atomicAdd(o + 2, s.z);
    atomicAdd(o + 3, s.w);
}

// ---------------------------------------------------------------------------
extern "C" void kernel_launch(void* const* d_in, const int* in_sizes, int n_in,
                              void* d_out, int out_size, void* d_ws, size_t ws_size,
                              hipStream_t stream) {
    const float* x  = (const float*)d_in[0];  // 1024x512
    const float* ne = (const float*)d_in[1];  // 255x512
    const float* lW = (const float*)d_in[2];  // 20480x512
    const float* lb = (const float*)d_in[3];  // 20480
    // d_in[4] res_path: deterministic structure, traversed directly

    float* out0 = (float*)d_out;            // 1024x80
    float* out1 = out0 + (size_t)B_ * C_;   // 1024x255

    char* ws = (char*)d_ws;
    short* xb      = (short*)ws;                             // 1 MB
    short* neb     = (short*)(ws + (1u << 20));              // 256 KB
    float* p_ws    = (float*)(ws + (1u << 20) + (1u << 18)); // 1 MB
    short* wb      = (short*)(ws + (9u << 18));              // 20 MB @ 2.25 MB
    float* partial = (float*)(ws + (24u << 20));             // 21 MB (64x1024x80)

    convert_kernel<<<2304, 256, 0, stream>>>(lW, x, ne, wb, xb, neb);
    simgemm_kernel<<<64, 256, 0, stream>>>(xb, neb, out1);
    leafprob_kernel<<<B_, 256, 0, stream>>>(out1, p_ws, out0);
    gemm_kernel<<<512, 256, 0, stream>>>(xb, wb, p_ws, lb, partial);
    reduce_kernel<<<640, 256, 0, stream>>>(partial, out0);
}

// Round 5
// 137.120 us; speedup vs baseline: 1.2739x; 1.0247x over previous
//
#include <hip/hip_runtime.h>
#include <stdint.h>

// Problem constants
#define B_  1024
#define D_  512
#define K_  255
#define L_  256
#define C_  80

typedef __attribute__((ext_vector_type(8))) short bf16x8;
typedef __attribute__((ext_vector_type(4))) float f32x4;
typedef __attribute__((ext_vector_type(8))) short short8;

// async global->LDS, 16B per lane; dst must be wave-uniform base + lane*16.
#define GLD(gsrc, ldst) \
  __builtin_amdgcn_global_load_lds((const __attribute__((address_space(1))) void*)(gsrc), \
                                   (__attribute__((address_space(3))) void*)(ldst), 16, 0, 0)

__device__ __forceinline__ short cvt_bf16(float f) {
    unsigned u = __float_as_uint(f);
    u += 0x7FFFu + ((u >> 16) & 1u);
    return (short)(u >> 16);
}

// ---------------------------------------------------------------------------
// Kernel 1: convert W (20480x512) + x (1024x512) fp32->bf16, AND normalize
// ne rows -> bf16 neb (256 rows; row 255 zeroed).  Memory-bound (~66 MB),
// measured ~11 us ~= its 67 MB / 6.3 TB/s floor. Leave alone.
// ---------------------------------------------------------------------------
__global__ __launch_bounds__(256) void convert_kernel(const float* __restrict__ w,
                                                      const float* __restrict__ x,
                                                      const float* __restrict__ ne,
                                                      short* __restrict__ wb,
                                                      short* __restrict__ xb,
                                                      short* __restrict__ neb) {
    __shared__ float red[256];
    const int tid = threadIdx.x;
    if (blockIdx.x < 2048) {
        size_t i0 = (size_t)blockIdx.x * 256 + tid;
        const size_t stride = 2048u * 256u;
        for (size_t v = i0; v < 1310720u; v += stride) {
            float4 a = ((const float4*)w)[v * 2];
            float4 b = ((const float4*)w)[v * 2 + 1];
            short8 o;
            o[0] = cvt_bf16(a.x); o[1] = cvt_bf16(a.y); o[2] = cvt_bf16(a.z); o[3] = cvt_bf16(a.w);
            o[4] = cvt_bf16(b.x); o[5] = cvt_bf16(b.y); o[6] = cvt_bf16(b.z); o[7] = cvt_bf16(b.w);
            ((short8*)wb)[v] = o;
        }
        for (size_t v = i0; v < 65536u; v += stride) {
            float4 a = ((const float4*)x)[v * 2];
            float4 b = ((const float4*)x)[v * 2 + 1];
            short8 o;
            o[0] = cvt_bf16(a.x); o[1] = cvt_bf16(a.y); o[2] = cvt_bf16(a.z); o[3] = cvt_bf16(a.w);
            o[4] = cvt_bf16(b.x); o[5] = cvt_bf16(b.y); o[6] = cvt_bf16(b.z); o[7] = cvt_bf16(b.w);
            ((short8*)xb)[v] = o;
        }
    } else {
        const int row = blockIdx.x - 2048;  // 0..255
        if (row == 255) {
            ((unsigned*)(neb + 255 * 512))[tid] = 0u;  // pad row = zeros
            return;
        }
        const float2* nr = (const float2*)(ne + (size_t)row * 512);
        float2 a = nr[tid];
        red[tid] = a.x * a.x + a.y * a.y;
        __syncthreads();
        #pragma unroll
        for (int s = 128; s > 0; s >>= 1) {
            if (tid < s) red[tid] += red[tid + s];
            __syncthreads();
        }
        float inv = rsqrtf(red[0]);
        unsigned lo = (unsigned short)cvt_bf16(a.x * inv);
        unsigned hi = (unsigned short)cvt_bf16(a.y * inv);
        ((unsigned*)(neb + (size_t)row * 512))[tid] = lo | (hi << 16);
    }
}

// ---------------------------------------------------------------------------
// Kernel 2: sim GEMM: out1[b,k] = sigmoid(xb[b,:]·neb[k,:]). 64x64 tiles.
// ---------------------------------------------------------------------------
__global__ __launch_bounds__(256) void simgemm_kernel(const short* __restrict__ xb,
                                                      const short* __restrict__ neb,
                                                      float* __restrict__ out1) {
    __shared__ __align__(16) short Ald[512 * 8];
    __shared__ __align__(16) short Bld[512 * 8];
    const int tid = threadIdx.x;
    const int lane = tid & 63, wave = tid >> 6;
    const int q = lane >> 4, r = lane & 15;
    const int mt = blockIdx.x >> 2;
    const int nt = blockIdx.x & 3;

    f32x4 acc[4];
    #pragma unroll
    for (int nf = 0; nf < 4; ++nf) acc[nf] = (f32x4){0.f, 0.f, 0.f, 0.f};

    const bf16x8* Av = (const bf16x8*)Ald;
    const bf16x8* Bv = (const bf16x8*)Bld;

    for (int kb = 0; kb < 8; ++kb) {
        __syncthreads();
        #pragma unroll
        for (int j = 0; j < 2; ++j) {
            int ph = j * 256 + tid, rr = ph >> 3, g = (ph & 7) ^ (rr & 7);
            GLD(xb + ((size_t)(mt * 64 + rr) * D_ + kb * 64 + g * 8), Ald + ph * 8);
        }
        #pragma unroll
        for (int j = 0; j < 2; ++j) {
            int ph = j * 256 + tid, cc = ph >> 3, g = (ph & 7) ^ (cc & 7);
            GLD(neb + ((size_t)(nt * 64 + cc) * D_ + kb * 64 + g * 8), Bld + ph * 8);
        }
        __syncthreads();
        #pragma unroll
        for (int ks = 0; ks < 2; ++ks) {
            const int g = ks * 4 + q;
            int rl = wave * 16 + r;
            bf16x8 af = Av[rl * 8 + (g ^ (rl & 7))];
            #pragma unroll
            for (int nf = 0; nf < 4; ++nf) {
                int cl = nf * 16 + r;
                bf16x8 bfr = Bv[cl * 8 + (g ^ (cl & 7))];
                acc[nf] = __builtin_amdgcn_mfma_f32_16x16x32_bf16(af, bfr, acc[nf], 0, 0, 0);
            }
        }
    }
    #pragma unroll
    for (int nf = 0; nf < 4; ++nf) {
        int gcol = nt * 64 + nf * 16 + r;
        if (gcol < K_) {
            #pragma unroll
            for (int i = 0; i < 4; ++i) {
                int grow = mt * 64 + wave * 16 + q * 4 + i;
                out1[(size_t)grow * K_ + gcol] = 1.f / (1.f + __expf(-acc[nf][i]));
            }
        }
    }
}

// ---------------------------------------------------------------------------
// Kernel 3: leaf probabilities from out1 sigmoids. Block = batch row.
// Also zeroes out0 (runs before gemm/reduce; reduce atomicAdds into it).
// ---------------------------------------------------------------------------
__global__ __launch_bounds__(256) void leafprob_kernel(const float* __restrict__ out1,
                                                       float* __restrict__ p_ws,
                                                       float* __restrict__ out0) {
    __shared__ float ss[K_];
    const int b = blockIdx.x, t = threadIdx.x;
    if (t < K_) ss[t] = out1[(size_t)b * K_ + t];
    if (t < C_) out0[(size_t)b * C_ + t] = 0.f;   // zero-init for reduce atomics
    __syncthreads();
    float prob = 1.f;
    int node = 0;
    #pragma unroll
    for (int d = 0; d < 8; ++d) {
        int bit = (t >> (7 - d)) & 1;
        float s = ss[node];
        prob *= bit ? (1.f - s) : s;
        node = 2 * node + 1 + bit;
    }
    p_ws[(size_t)b * L_ + t] = prob;
}

// ---------------------------------------------------------------------------
// Kernel 4: main GEMM — round-4 structure with DOUBLE-SIZE STAGES.
// Round-5 theory: per-CU accounting shows 2660 cyc/stage-slot vs ~650 of
// work; the residual is the vmcnt(0) drain (last GLD's full latency +
// delivery tail) exposed at EVERY stage barrier, x16 per block. Proven
// lever (r0 -> r4): amortize the drain over more MFMA per barrier.
// Change: each stage stages TWO leaves of B (40 KB, Bld split in halves)
// and computes 80 MFMA; stage count 16 -> 8, drain exposures halved.
// The two leaves are processed SEQUENTIALLY with the same dec[2][5]
// register block -> peak registers identical to round 4 (VGPR 128, the
// proven no-spill shape; round-1's pv-in-regs spill lesson respected).
// Sync rhythm per stage is IDENTICAL to round 4 (barrier; stage; barrier;
// compute) — inherits its verification.
// LDS: A 32 KB + B 2x20 KB + p 2 KB = 74 KB -> 2 blocks/CU at (256,2).
// Grid = mt(8) x lc(64) = 512 blocks; blockIdx%8 = lc%8 keeps the 8
// m-tiles sharing a W slab on one XCD (~2.6 MB/XCD, L2-resident).
// ---------------------------------------------------------------------------
__global__ __launch_bounds__(256, 2) void gemm_kernel(const short* __restrict__ xb,
                                                      const short* __restrict__ wb,
                                                      const float* __restrict__ p,
                                                      const float* __restrict__ lb,
                                                      float* __restrict__ partial) {
    __shared__ __align__(16) short Ald[2048 * 8];      // 128 rows x 16 granules = 32 KB
    __shared__ __align__(16) short Bld[2 * 1280 * 8];  // 2 leaves x 80 rows x 16 g = 40 KB
    __shared__ float p_ld[128][4];                     // 2 KB

    const int tid = threadIdx.x;
    const int lane = tid & 63, wave = tid >> 6;
    const int q = lane >> 4, r = lane & 15;
    const int wrow = wave * 32;
    const int lc = blockIdx.x & 63;   // 64 l-chunks of 4 leaves
    const int mt = blockIdx.x >> 6;   // 8 m-tiles of 128 rows

    if (tid < 128) {
        float4 pw = *(const float4*)(p + (size_t)(mt * 128 + tid) * L_ + lc * 4);
        p_ld[tid][0] = pw.x; p_ld[tid][1] = pw.y;
        p_ld[tid][2] = pw.z; p_ld[tid][3] = pw.w;
    }
    __syncthreads();  // p_ld visible

    // outacc init = bias term: sum_li p_ld[row][li] * lb[(lc*4+li)*80 + col]
    f32x4 outacc[2][5];
    #pragma unroll
    for (int nf = 0; nf < 5; ++nf) {
        float bv[4];
        #pragma unroll
        for (int li = 0; li < 4; ++li)
            bv[li] = lb[(size_t)(lc * 4 + li) * C_ + nf * 16 + r];
        #pragma unroll
        for (int mf = 0; mf < 2; ++mf)
            #pragma unroll
            for (int i = 0; i < 4; ++i) {
                int row = wrow + mf * 16 + q * 4 + i;
                outacc[mf][nf][i] = p_ld[row][0] * bv[0] + p_ld[row][1] * bv[1]
                                  + p_ld[row][2] * bv[2] + p_ld[row][3] * bv[3];
            }
    }

    const bf16x8* Av = (const bf16x8*)Ald;
    const f32x4 z4 = {0.f, 0.f, 0.f, 0.f};

    for (int kb = 0; kb < 4; ++kb) {      // 4 K=128 chunks, A staged once each
        for (int lp = 0; lp < 2; ++lp) {  // 2 leaf-PAIRS per kb -> 8 stages total
            __syncthreads();  // previous stage's readers done before overwrite
            if (lp == 0) {
                // stage A: 2048 granules (128 rows x 16), 8 per thread
                #pragma unroll
                for (int j = 0; j < 8; ++j) {
                    int ph = j * 256 + tid;
                    int rr = ph >> 4;
                    int g  = (ph & 15) ^ (rr & 15);
                    GLD(xb + ((size_t)(mt * 128 + rr) * D_ + kb * 128 + g * 8), Ald + ph * 8);
                }
            }
            // stage B: TWO leaves, 2 x 1280 granules (80 rows x 16), 10/thread
            #pragma unroll
            for (int l2 = 0; l2 < 2; ++l2) {
                const int l = lc * 4 + lp * 2 + l2;
                #pragma unroll
                for (int j = 0; j < 5; ++j) {
                    int ph = j * 256 + tid;
                    int cc = ph >> 4;
                    int g  = (ph & 15) ^ (cc & 15);
                    GLD(wb + ((size_t)(l * C_ + cc) * D_ + kb * 128 + g * 8),
                        Bld + (l2 * 1280 + ph) * 8);
                }
            }
            __syncthreads();  // drains vmcnt(0): tiles complete

            // process the two staged leaves SEQUENTIALLY (same dec regs)
            #pragma unroll
            for (int l2 = 0; l2 < 2; ++l2) {
                const bf16x8* Bv = (const bf16x8*)Bld + l2 * 1280;
                const int li = lp * 2 + l2;

                f32x4 dec[2][5];
                #pragma unroll
                for (int ks = 0; ks < 4; ++ks) {  // 4 K=32 slices -> 40 MFMA/leaf
                    const int g = ks * 4 + q;
                    bf16x8 af[2], bfr[5];
                    #pragma unroll
                    for (int mf = 0; mf < 2; ++mf) {
                        int rl = wrow + mf * 16 + r;
                        af[mf] = Av[rl * 16 + (g ^ (rl & 15))];
                    }
                    #pragma unroll
                    for (int nf = 0; nf < 5; ++nf) {
                        int cl = nf * 16 + r;
                        bfr[nf] = Bv[cl * 16 + (g ^ (cl & 15))];
                    }
                    #pragma unroll
                    for (int mf = 0; mf < 2; ++mf)
                        #pragma unroll
                        for (int nf = 0; nf < 5; ++nf)
                            dec[mf][nf] = __builtin_amdgcn_mfma_f32_16x16x32_bf16(
                                af[mf], bfr[nf], ks == 0 ? z4 : dec[mf][nf], 0, 0, 0);
                }

                // linear p-fold of this (kb,li) chunk; p read from LDS
                #pragma unroll
                for (int mf = 0; mf < 2; ++mf)
                    #pragma unroll
                    for (int i = 0; i < 4; ++i) {
                        float pf = p_ld[wrow + mf * 16 + q * 4 + i][li];
                        #pragma unroll
                        for (int nf = 0; nf < 5; ++nf)
                            outacc[mf][nf][i] += pf * dec[mf][nf][i];
                    }
            }
        }
    }

    // store partials: partial[lc][1024 rows][80 cols], this block owns 128 rows
    const size_t rbase = (size_t)lc * B_ + mt * 128;
    #pragma unroll
    for (int mf = 0; mf < 2; ++mf)
        #pragma unroll
        for (int nf = 0; nf < 5; ++nf)
            #pragma unroll
            for (int i = 0; i < 4; ++i) {
                int row = wrow + mf * 16 + q * 4 + i;
                int col = nf * 16 + r;
                partial[(rbase + row) * C_ + col] = outacc[mf][nf][i];
            }
}

// ---------------------------------------------------------------------------
// Kernel 5: reduce 64 lc partials -> out0 (1024x80).
// Grid 640 = 80 idx-chunks x 8 j-groups: each thread sums 8 slabs and
// atomicAdds (8-way contention only; out0 zeroed by leafprob).
// ---------------------------------------------------------------------------
__global__ __launch_bounds__(256) void reduce_kernel(const float* __restrict__ partial,
                                                     float* __restrict__ out0) {
    const int chunk = blockIdx.x >> 3;            // 0..79
    const int jg    = blockIdx.x & 7;             // 0..7
    const int idx   = chunk * 256 + threadIdx.x;  // float4 index < 20480
    const float4* p4 = (const float4*)partial;
    float4 s = {0.f, 0.f, 0.f, 0.f};
    #pragma unroll
    for (int j = 0; j < 8; ++j) {
        float4 v = p4[(size_t)(jg * 8 + j) * (B_ * C_ / 4) + idx];
        s.x += v.x; s.y += v.y; s.z += v.z; s.w += v.w;
    }
    float* o = out0 + (size_t)idx * 4;
    atomicAdd(o + 0, s.x);
    atomicAdd(o + 1, s.y);
    atomicAdd(o + 2, s.z);
    atomicAdd(o + 3, s.w);
}

// ---------------------------------------------------------------------------
extern "C" void kernel_launch(void* const* d_in, const int* in_sizes, int n_in,
                              void* d_out, int out_size, void* d_ws, size_t ws_size,
                              hipStream_t stream) {
    const float* x  = (const float*)d_in[0];  // 1024x512
    const float* ne = (const float*)d_in[1];  // 255x512
    const float* lW = (const float*)d_in[2];  // 20480x512
    const float* lb = (const float*)d_in[3];  // 20480
    // d_in[4] res_path: deterministic structure, traversed directly

    float* out0 = (float*)d_out;            // 1024x80
    float* out1 = out0 + (size_t)B_ * C_;   // 1024x255

    char* ws = (char*)d_ws;
    short* xb      = (short*)ws;                             // 1 MB
    short* neb     = (short*)(ws + (1u << 20));              // 256 KB
    float* p_ws    = (float*)(ws + (1u << 20) + (1u << 18)); // 1 MB
    short* wb      = (short*)(ws + (9u << 18));              // 20 MB @ 2.25 MB
    float* partial = (float*)(ws + (24u << 20));             // 21 MB (64x1024x80)

    convert_kernel<<<2304, 256, 0, stream>>>(lW, x, ne, wb, xb, neb);
    simgemm_kernel<<<64, 256, 0, stream>>>(xb, neb, out1);
    leafprob_kernel<<<B_, 256, 0, stream>>>(out1, p_ws, out0);
    gemm_kernel<<<512, 256, 0, stream>>>(xb, wb, p_ws, lb, partial);
    reduce_kernel<<<640, 256, 0, stream>>>(partial, out0);
}